// Round 2
// baseline (243.170 us; speedup 1.0000x reference)
//
#include <hip/hip_runtime.h>
#include <hip/hip_fp16.h>

#define BB 4
#define SS 4096
#define DD 64

typedef _Float16 half8 __attribute__((ext_vector_type(8)));
typedef float floatx4 __attribute__((ext_vector_type(4)));

// Kernel A: Q = X*R, K = X*E in fp32, stored as hi/lo fp16 pairs (Markidis split)
// so QK^T via 3 fp16 MFMAs is fp32-accurate. Vt[b][d][s] = X[b][s][d] in fp16.
__global__ __launch_bounds__(256) void proj_kernel(
    const float* __restrict__ X, const float* __restrict__ R, const float* __restrict__ E,
    _Float16* __restrict__ Qhi, _Float16* __restrict__ Qlo,
    _Float16* __restrict__ Khi, _Float16* __restrict__ Klo,
    _Float16* __restrict__ Vt)
{
    __shared__ float Xs[64][68];   // pad 68: float4-aligned, breaks stride-64 conflicts
    __shared__ float Rs[64][64];
    __shared__ float Es[64][64];
    int t = threadIdx.x;
    long rowbase = (long)blockIdx.x * 64;

    const float4* Xg = (const float4*)(X + rowbase * 64);
    for (int j = 0; j < 4; ++j) {
        int idx = j * 256 + t;          // 1024 float4 per 64x64 tile, coalesced
        int r = idx >> 4;
        int c = (idx & 15) * 4;
        *(float4*)&Xs[r][c] = Xg[idx];
        *(float4*)&Rs[r][c] = ((const float4*)R)[idx];
        *(float4*)&Es[r][c] = ((const float4*)E)[idx];
    }
    __syncthreads();

    int row = t >> 2;
    int c0 = (t & 3) * 16;
    float q[16], k[16];
    for (int i = 0; i < 16; ++i) { q[i] = 0.f; k[i] = 0.f; }
    for (int d = 0; d < 64; ++d) {
        float x = Xs[row][d];
        for (int i = 0; i < 16; ++i) {
            q[i] = fmaf(x, Rs[d][c0 + i], q[i]);
            k[i] = fmaf(x, Es[d][c0 + i], k[i]);
        }
    }
    long gq = (rowbase + row) * 64 + c0;
    for (int i = 0; i < 16; ++i) {
        _Float16 qh = (_Float16)q[i];
        _Float16 kh = (_Float16)k[i];
        Qhi[gq + i] = qh;
        Qlo[gq + i] = (_Float16)(q[i] - (float)qh);
        Khi[gq + i] = kh;
        Klo[gq + i] = (_Float16)(k[i] - (float)kh);
    }

    // V^T: Vt[b][d][sbase+s0..+15] = Xs[s][d]
    int d = t >> 2;
    int s0 = (t & 3) * 16;
    int b = (int)(rowbase >> 12);
    int sbase = (int)(rowbase & 4095);
    _Float16* vp = Vt + ((long)(b * 64 + d)) * SS + sbase + s0;
    for (int i = 0; i < 16; ++i)
        vp[i] = (_Float16)Xs[s0 + i][d];
}

#define L2E 1.44269504088896340736f

// Kernel B: flash attention. Block = 64 queries (4 waves x 16), loop over 64-key tiles.
__global__ __launch_bounds__(256) void attn_kernel(
    const _Float16* __restrict__ Qhi, const _Float16* __restrict__ Qlo,
    const _Float16* __restrict__ Khi, const _Float16* __restrict__ Klo,
    const _Float16* __restrict__ Vt, float* __restrict__ Out)
{
    __shared__ _Float16 Ksh[64][64];     // [key][d] hi
    __shared__ _Float16 Ksl[64][64];     // [key][d] lo
    __shared__ _Float16 Vs[64][64];      // [d][key]  (from Vt)
    __shared__ _Float16 Ps[4][16][64];   // per-wave P tile, C-layout -> A-layout round trip

    int t = threadIdx.x;
    int wave = t >> 6;
    int lane = t & 63;
    int l15 = lane & 15;
    int quad = lane >> 4;
    int b = blockIdx.y;
    int q0 = blockIdx.x * 64 + wave * 16;

    // Persistent Q A-fragments: A[m=l15][k=quad*8+j], row-major Q -> contiguous 16B
    long qrow = ((long)b * SS + q0 + l15) * DD;
    half8 qa0h = *(const half8*)(Qhi + qrow + quad * 8);
    half8 qa1h = *(const half8*)(Qhi + qrow + 32 + quad * 8);
    half8 qa0l = *(const half8*)(Qlo + qrow + quad * 8);
    half8 qa1l = *(const half8*)(Qlo + qrow + 32 + quad * 8);

    floatx4 o[4];
    for (int i = 0; i < 4; ++i) o[i] = (floatx4){0.f, 0.f, 0.f, 0.f};
    float m_r[4] = {-1e30f, -1e30f, -1e30f, -1e30f};
    float l_r[4] = {0.f, 0.f, 0.f, 0.f};

    const float scale = 0.125f * L2E;   // 1/sqrt(64), folded with log2(e) -> exp2 domain

    for (int kt = 0; kt < SS / 64; ++kt) {
        // stage K hi/lo tiles and Vt tile (each thread: 2x16B per array, coalesced)
        {
            int rr = t >> 2;
            int cc = (t & 3) * 16;
            long koff = ((long)b * SS + kt * 64 + rr) * DD + cc;
            const uint4* khsrc = (const uint4*)(Khi + koff);
            uint4* khdst = (uint4*)&Ksh[rr][cc];
            khdst[0] = khsrc[0]; khdst[1] = khsrc[1];
            const uint4* klsrc = (const uint4*)(Klo + koff);
            uint4* kldst = (uint4*)&Ksl[rr][cc];
            kldst[0] = klsrc[0]; kldst[1] = klsrc[1];
            const uint4* vsrc = (const uint4*)(Vt + ((long)b * 64 + rr) * SS + kt * 64 + cc);
            uint4* vdst = (uint4*)&Vs[rr][cc];
            vdst[0] = vsrc[0]; vdst[1] = vsrc[1];
        }
        __syncthreads();

        // S = Q K^T (fp32-accurate via hi/lo split): hh + h*lo + lo*h
        floatx4 s[4];
        for (int ct = 0; ct < 4; ++ct) {
            floatx4 acc = {0.f, 0.f, 0.f, 0.f};
            half8 kb0h = *(const half8*)&Ksh[ct * 16 + l15][quad * 8];
            half8 kb1h = *(const half8*)&Ksh[ct * 16 + l15][32 + quad * 8];
            half8 kb0l = *(const half8*)&Ksl[ct * 16 + l15][quad * 8];
            half8 kb1l = *(const half8*)&Ksl[ct * 16 + l15][32 + quad * 8];
            acc = __builtin_amdgcn_mfma_f32_16x16x32_f16(qa0h, kb0h, acc, 0, 0, 0);
            acc = __builtin_amdgcn_mfma_f32_16x16x32_f16(qa1h, kb1h, acc, 0, 0, 0);
            acc = __builtin_amdgcn_mfma_f32_16x16x32_f16(qa0h, kb0l, acc, 0, 0, 0);
            acc = __builtin_amdgcn_mfma_f32_16x16x32_f16(qa1h, kb1l, acc, 0, 0, 0);
            acc = __builtin_amdgcn_mfma_f32_16x16x32_f16(qa0l, kb0h, acc, 0, 0, 0);
            acc = __builtin_amdgcn_mfma_f32_16x16x32_f16(qa1l, kb1h, acc, 0, 0, 0);
            s[ct] = acc;
        }

        // online softmax in registers; C-layout row = quad*4 + r, col = l15 (+16*ct)
        float p[4][4];
        for (int r = 0; r < 4; ++r) {
            float mt = fmaxf(fmaxf(s[0][r], s[1][r]), fmaxf(s[2][r], s[3][r]));
            for (int off = 8; off; off >>= 1)
                mt = fmaxf(mt, __shfl_xor(mt, off));
            mt *= scale;
            float mn = fmaxf(m_r[r], mt);
            float alpha = exp2f(m_r[r] - mn);   // exp2f(-1e30 - mn) == 0 on first tile
            m_r[r] = mn;
            float rs = 0.f;
            for (int ct = 0; ct < 4; ++ct) {
                float pv = exp2f(s[ct][r] * scale - mn);
                p[ct][r] = pv;
                rs += pv;
            }
            for (int off = 8; off; off >>= 1)
                rs += __shfl_xor(rs, off);
            l_r[r] = l_r[r] * alpha + rs;
            for (int dt = 0; dt < 4; ++dt) o[dt][r] *= alpha;
        }

        // P: C-layout -> A-layout via per-wave LDS (wave-local, no barrier needed)
        for (int ct = 0; ct < 4; ++ct)
            for (int r = 0; r < 4; ++r)
                Ps[wave][quad * 4 + r][ct * 16 + l15] = (_Float16)p[ct][r];

        // O += P V : A[m=l15][k=key], B[k=key][n=d] = Vs[d][key] rows
        for (int h = 0; h < 2; ++h) {
            half8 pa = *(const half8*)&Ps[wave][l15][h * 32 + quad * 8];
            for (int dt = 0; dt < 4; ++dt) {
                half8 vb = *(const half8*)&Vs[dt * 16 + l15][h * 32 + quad * 8];
                o[dt] = __builtin_amdgcn_mfma_f32_16x16x32_f16(pa, vb, o[dt], 0, 0, 0);
            }
        }
        __syncthreads();   // protect Ks/Vs before next stage
    }

    // epilogue: O / l, fp32 store
    for (int r = 0; r < 4; ++r) {
        float inv = 1.f / l_r[r];
        long orow = ((long)b * SS + q0 + quad * 4 + r) * DD;
        for (int dt = 0; dt < 4; ++dt)
            Out[orow + dt * 16 + l15] = o[dt][r] * inv;
    }
}

extern "C" void kernel_launch(void* const* d_in, const int* in_sizes, int n_in,
                              void* d_out, int out_size, void* d_ws, size_t ws_size,
                              hipStream_t stream) {
    const float* X = (const float*)d_in[0];
    const float* R = (const float*)d_in[1];
    const float* E = (const float*)d_in[2];
    float* Out = (float*)d_out;

    const size_t N = (size_t)BB * SS * DD;
    _Float16* Qhi = (_Float16*)d_ws;       // 2 MB each
    _Float16* Qlo = Qhi + N;
    _Float16* Khi = Qlo + N;
    _Float16* Klo = Khi + N;
    _Float16* Vt  = Klo + N;               // 10 MB total in d_ws

    proj_kernel<<<dim3(BB * SS / 64), 256, 0, stream>>>(X, R, E, Qhi, Qlo, Khi, Klo, Vt);
    attn_kernel<<<dim3(SS / 64, BB), 256, 0, stream>>>(Qhi, Qlo, Khi, Klo, Vt, Out);
}

// Round 3
// 148.275 us; speedup vs baseline: 1.6400x; 1.6400x over previous
//
#include <hip/hip_runtime.h>
#include <hip/hip_fp16.h>

#define BB 4
#define SS 4096
#define DD 64
#define NSPLIT 4                 // K-split factor: grid 256 -> 1024 blocks (4/CU)
#define KT_PER (SS / 64 / NSPLIT)

typedef _Float16 half8 __attribute__((ext_vector_type(8)));
typedef _Float16 half4 __attribute__((ext_vector_type(4)));
typedef float floatx4 __attribute__((ext_vector_type(4)));

// Kernel A: Q = X*R, K = X*E in fp32, stored as hi/lo fp16 pairs (Markidis split).
// 16 rows/block -> 4096 blocks (vs 256 before: was 1 block/CU, latency-bound at 65us).
__global__ __launch_bounds__(256) void proj_kernel(
    const float* __restrict__ X, const float* __restrict__ R, const float* __restrict__ E,
    _Float16* __restrict__ Qhi, _Float16* __restrict__ Qlo,
    _Float16* __restrict__ Khi, _Float16* __restrict__ Klo,
    _Float16* __restrict__ Vt)
{
    __shared__ float Rs[64][64];
    __shared__ float Es[64][64];
    __shared__ float Xs[16][68];     // pad 68 breaks stride-64 conflicts on transposed reads
    int t = threadIdx.x;
    long rowbase = (long)blockIdx.x * 16;

    for (int j = 0; j < 4; ++j) {
        int idx = j * 256 + t;       // 1024 float4 per 64x64 matrix
        int r = idx >> 4;
        int c = (idx & 15) * 4;
        *(float4*)&Rs[r][c] = ((const float4*)R)[idx];
        *(float4*)&Es[r][c] = ((const float4*)E)[idx];
    }
    *(float4*)&Xs[t >> 4][(t & 15) * 4] = ((const float4*)(X + rowbase * 64))[t];
    __syncthreads();

    int row = t >> 4;                // 0..15
    int c0 = (t & 15) * 4;           // 0..60
    float q[4] = {0.f, 0.f, 0.f, 0.f}, k[4] = {0.f, 0.f, 0.f, 0.f};
    for (int d = 0; d < 64; ++d) {
        float x = Xs[row][d];
        for (int j = 0; j < 4; ++j) {
            q[j] = fmaf(x, Rs[d][c0 + j], q[j]);
            k[j] = fmaf(x, Es[d][c0 + j], k[j]);
        }
    }
    long gq = (rowbase + row) * 64 + c0;
    half4 qh, ql, kh, kl;
    for (int j = 0; j < 4; ++j) {
        _Float16 h = (_Float16)q[j];
        qh[j] = h; ql[j] = (_Float16)(q[j] - (float)h);
        h = (_Float16)k[j];
        kh[j] = h; kl[j] = (_Float16)(k[j] - (float)h);
    }
    *(half4*)(Qhi + gq) = qh; *(half4*)(Qlo + gq) = ql;
    *(half4*)(Khi + gq) = kh; *(half4*)(Klo + gq) = kl;

    // V^T: Vt[b][d][s] = X[b][s][d] fp16 (Xs read-only since sync; no extra barrier)
    int d = t >> 2;                  // 0..63
    int si = (t & 3) * 4;            // 0..12
    int b = (int)(rowbase >> 12);
    int sbase = (int)(rowbase & 4095);
    half4 v;
    for (int j = 0; j < 4; ++j) v[j] = (_Float16)Xs[si + j][d];
    *(half4*)(Vt + ((long)(b * 64 + d)) * SS + sbase + si) = v;
}

#define L2E 1.44269504088896340736f
#define PD 72   // LDS row pad: 144B stride = 36 banks = 4 mod 32 -> 2-way (free) vs 16-way

// Kernel B: flash attention partial over 1/NSPLIT of the keys.
// Block = 64 queries (4 waves x 16). Writes unnormalized O plus (m, l) per row.
__global__ __launch_bounds__(256) void attn_partial(
    const _Float16* __restrict__ Qhi, const _Float16* __restrict__ Qlo,
    const _Float16* __restrict__ Khi, const _Float16* __restrict__ Klo,
    const _Float16* __restrict__ Vt,
    float* __restrict__ Op, float* __restrict__ Mp, float* __restrict__ Lp)
{
    __shared__ _Float16 Ksh[64][PD];
    __shared__ _Float16 Ksl[64][PD];
    __shared__ _Float16 Vs[64][PD];
    __shared__ _Float16 Ps[4][16][PD];

    int t = threadIdx.x;
    int wave = t >> 6;
    int lane = t & 63;
    int l15 = lane & 15;
    int quad = lane >> 4;
    int split = blockIdx.y;
    int b = blockIdx.z;
    int q0 = blockIdx.x * 64 + wave * 16;

    long qrow = ((long)b * SS + q0 + l15) * DD;
    half8 qa0h = *(const half8*)(Qhi + qrow + quad * 8);
    half8 qa1h = *(const half8*)(Qhi + qrow + 32 + quad * 8);
    half8 qa0l = *(const half8*)(Qlo + qrow + quad * 8);
    half8 qa1l = *(const half8*)(Qlo + qrow + 32 + quad * 8);

    floatx4 o[4];
    for (int i = 0; i < 4; ++i) o[i] = (floatx4){0.f, 0.f, 0.f, 0.f};
    float m_r[4] = {-1e30f, -1e30f, -1e30f, -1e30f};
    float l_r[4] = {0.f, 0.f, 0.f, 0.f};

    const float scale = 0.125f * L2E;

    for (int kt = split * KT_PER; kt < (split + 1) * KT_PER; ++kt) {
        {
            int rr = t >> 2;
            int cc = (t & 3) * 16;
            long koff = ((long)b * SS + kt * 64 + rr) * DD + cc;
            const uint4* khsrc = (const uint4*)(Khi + koff);
            uint4* khdst = (uint4*)&Ksh[rr][cc];
            khdst[0] = khsrc[0]; khdst[1] = khsrc[1];
            const uint4* klsrc = (const uint4*)(Klo + koff);
            uint4* kldst = (uint4*)&Ksl[rr][cc];
            kldst[0] = klsrc[0]; kldst[1] = klsrc[1];
            const uint4* vsrc = (const uint4*)(Vt + ((long)b * 64 + rr) * SS + kt * 64 + cc);
            uint4* vdst = (uint4*)&Vs[rr][cc];
            vdst[0] = vsrc[0]; vdst[1] = vsrc[1];
        }
        __syncthreads();

        // S = Q K^T, fp32-accurate: hh + h*lo + lo*h
        floatx4 s[4];
        for (int ct = 0; ct < 4; ++ct) {
            floatx4 acc = {0.f, 0.f, 0.f, 0.f};
            half8 kb0h = *(const half8*)&Ksh[ct * 16 + l15][quad * 8];
            half8 kb1h = *(const half8*)&Ksh[ct * 16 + l15][32 + quad * 8];
            half8 kb0l = *(const half8*)&Ksl[ct * 16 + l15][quad * 8];
            half8 kb1l = *(const half8*)&Ksl[ct * 16 + l15][32 + quad * 8];
            acc = __builtin_amdgcn_mfma_f32_16x16x32_f16(qa0h, kb0h, acc, 0, 0, 0);
            acc = __builtin_amdgcn_mfma_f32_16x16x32_f16(qa1h, kb1h, acc, 0, 0, 0);
            acc = __builtin_amdgcn_mfma_f32_16x16x32_f16(qa0h, kb0l, acc, 0, 0, 0);
            acc = __builtin_amdgcn_mfma_f32_16x16x32_f16(qa1h, kb1l, acc, 0, 0, 0);
            acc = __builtin_amdgcn_mfma_f32_16x16x32_f16(qa0l, kb0h, acc, 0, 0, 0);
            acc = __builtin_amdgcn_mfma_f32_16x16x32_f16(qa1l, kb1h, acc, 0, 0, 0);
            s[ct] = acc;
        }

        // online softmax; C-layout row = quad*4 + r, col = l15 (+16*ct)
        float p[4][4];
        for (int r = 0; r < 4; ++r) {
            float mt = fmaxf(fmaxf(s[0][r], s[1][r]), fmaxf(s[2][r], s[3][r]));
            for (int off = 8; off; off >>= 1)
                mt = fmaxf(mt, __shfl_xor(mt, off));
            mt *= scale;
            float mn = fmaxf(m_r[r], mt);
            float alpha = exp2f(m_r[r] - mn);
            m_r[r] = mn;
            float rs = 0.f;
            for (int ct = 0; ct < 4; ++ct) {
                float pv = exp2f(s[ct][r] * scale - mn);
                p[ct][r] = pv;
                rs += pv;
            }
            for (int off = 8; off; off >>= 1)
                rs += __shfl_xor(rs, off);
            l_r[r] = l_r[r] * alpha + rs;
            for (int dt = 0; dt < 4; ++dt) o[dt][r] *= alpha;
        }

        // P: C-layout -> A-layout via per-wave LDS
        for (int ct = 0; ct < 4; ++ct)
            for (int r = 0; r < 4; ++r)
                Ps[wave][quad * 4 + r][ct * 16 + l15] = (_Float16)p[ct][r];

        for (int h = 0; h < 2; ++h) {
            half8 pa = *(const half8*)&Ps[wave][l15][h * 32 + quad * 8];
            for (int dt = 0; dt < 4; ++dt) {
                half8 vb = *(const half8*)&Vs[dt * 16 + l15][h * 32 + quad * 8];
                o[dt] = __builtin_amdgcn_mfma_f32_16x16x32_f16(pa, vb, o[dt], 0, 0, 0);
            }
        }
        __syncthreads();
    }

    // store unnormalized partial O and per-row (m, l)
    long pbase = ((long)b * NSPLIT + split) * SS;
    for (int r = 0; r < 4; ++r) {
        int q = q0 + quad * 4 + r;
        long orow = (pbase + q) * DD;
        for (int dt = 0; dt < 4; ++dt)
            Op[orow + dt * 16 + l15] = o[dt][r];
        if (l15 == 0) {
            Mp[pbase + q] = m_r[r];
            Lp[pbase + q] = l_r[r];
        }
    }
}

// Kernel C: merge NSPLIT partials per query row. 16 queries/block.
__global__ __launch_bounds__(256) void combine_kernel(
    const float* __restrict__ Op, const float* __restrict__ Mp,
    const float* __restrict__ Lp, float* __restrict__ Out)
{
    int t = threadIdx.x;
    int qi = t >> 4;
    int d4 = (t & 15) * 4;
    long gq = (long)blockIdx.x * 16 + qi;    // global row in [0, BB*SS)
    int b = (int)(gq >> 12);
    int s = (int)(gq & 4095);

    float m = -1e30f;
    for (int i = 0; i < NSPLIT; ++i)
        m = fmaxf(m, Mp[((long)b * NSPLIT + i) * SS + s]);
    float l = 0.f;
    float4 o = {0.f, 0.f, 0.f, 0.f};
    for (int i = 0; i < NSPLIT; ++i) {
        long pb = ((long)b * NSPLIT + i) * SS + s;
        float a = exp2f(Mp[pb] - m);
        l = fmaf(Lp[pb], a, l);
        float4 oi = *(const float4*)(Op + pb * DD + d4);
        o.x = fmaf(oi.x, a, o.x); o.y = fmaf(oi.y, a, o.y);
        o.z = fmaf(oi.z, a, o.z); o.w = fmaf(oi.w, a, o.w);
    }
    float inv = 1.f / l;
    float4 r = {o.x * inv, o.y * inv, o.z * inv, o.w * inv};
    *(float4*)(Out + gq * DD + d4) = r;
}

extern "C" void kernel_launch(void* const* d_in, const int* in_sizes, int n_in,
                              void* d_out, int out_size, void* d_ws, size_t ws_size,
                              hipStream_t stream) {
    const float* X = (const float*)d_in[0];
    const float* R = (const float*)d_in[1];
    const float* E = (const float*)d_in[2];
    float* Out = (float*)d_out;

    const size_t N = (size_t)BB * SS * DD;
    _Float16* Qhi = (_Float16*)d_ws;
    _Float16* Qlo = Qhi + N;
    _Float16* Khi = Qlo + N;
    _Float16* Klo = Khi + N;
    _Float16* Vt  = Klo + N;                      // 10 MB fp16
    float* Op = (float*)(Vt + N);                 // BB*NSPLIT*SS*DD fp32 = 16.8 MB
    float* Mp = Op + (size_t)BB * NSPLIT * SS * DD;
    float* Lp = Mp + (size_t)BB * NSPLIT * SS;    // total ~27.3 MB

    proj_kernel<<<dim3(BB * SS / 16), 256, 0, stream>>>(X, R, E, Qhi, Qlo, Khi, Klo, Vt);
    attn_partial<<<dim3(SS / 64, NSPLIT, BB), 256, 0, stream>>>(Qhi, Qlo, Khi, Klo, Vt, Op, Mp, Lp);
    combine_kernel<<<dim3(BB * SS / 16), 256, 0, stream>>>(Op, Mp, Lp, Out);
}

// Round 6
// 119.805 us; speedup vs baseline: 2.0297x; 1.2376x over previous
//
#include <hip/hip_runtime.h>
#include <hip/hip_fp16.h>

#define BB 4
#define SS 4096
#define DD 64
#define NSPLIT 4                 // K-split factor: 1024 blocks (4/CU)
#define KT_PER (SS / 64 / NSPLIT)

typedef _Float16 half8 __attribute__((ext_vector_type(8)));
typedef _Float16 half4 __attribute__((ext_vector_type(4)));
typedef __fp16 fp16x2 __attribute__((ext_vector_type(2)));   // cvt_pkrtz return type
typedef float floatx4 __attribute__((ext_vector_type(4)));

// Kernel A: Q = X*R, K = X*E in fp32, stored as hi/lo fp16 pairs (Markidis split).
__global__ __launch_bounds__(256) void proj_kernel(
    const float* __restrict__ X, const float* __restrict__ R, const float* __restrict__ E,
    _Float16* __restrict__ Qhi, _Float16* __restrict__ Qlo,
    _Float16* __restrict__ Khi, _Float16* __restrict__ Klo,
    _Float16* __restrict__ Vt)
{
    __shared__ float Rs[64][64];
    __shared__ float Es[64][64];
    __shared__ float Xs[16][68];     // pad 68 breaks stride-64 conflicts on transposed reads
    int t = threadIdx.x;
    long rowbase = (long)blockIdx.x * 16;

    for (int j = 0; j < 4; ++j) {
        int idx = j * 256 + t;       // 1024 float4 per 64x64 matrix
        int r = idx >> 4;
        int c = (idx & 15) * 4;
        *(float4*)&Rs[r][c] = ((const float4*)R)[idx];
        *(float4*)&Es[r][c] = ((const float4*)E)[idx];
    }
    *(float4*)&Xs[t >> 4][(t & 15) * 4] = ((const float4*)(X + rowbase * 64))[t];
    __syncthreads();

    int row = t >> 4;                // 0..15
    int c0 = (t & 15) * 4;           // 0..60
    float q[4] = {0.f, 0.f, 0.f, 0.f}, k[4] = {0.f, 0.f, 0.f, 0.f};
#pragma unroll 4
    for (int d = 0; d < 64; ++d) {
        float x = Xs[row][d];
        float4 rv = *(const float4*)&Rs[d][c0];   // ds_read_b128
        float4 ev = *(const float4*)&Es[d][c0];
        q[0] = fmaf(x, rv.x, q[0]); q[1] = fmaf(x, rv.y, q[1]);
        q[2] = fmaf(x, rv.z, q[2]); q[3] = fmaf(x, rv.w, q[3]);
        k[0] = fmaf(x, ev.x, k[0]); k[1] = fmaf(x, ev.y, k[1]);
        k[2] = fmaf(x, ev.z, k[2]); k[3] = fmaf(x, ev.w, k[3]);
    }
    long gq = (rowbase + row) * 64 + c0;
    half4 qh, ql, kh, kl;
    for (int j = 0; j < 4; ++j) {
        _Float16 h = (_Float16)q[j];
        qh[j] = h; ql[j] = (_Float16)(q[j] - (float)h);
        h = (_Float16)k[j];
        kh[j] = h; kl[j] = (_Float16)(k[j] - (float)h);
    }
    *(half4*)(Qhi + gq) = qh; *(half4*)(Qlo + gq) = ql;
    *(half4*)(Khi + gq) = kh; *(half4*)(Klo + gq) = kl;

    // V^T: Vt[b][d][s] = X[b][s][d] fp16
    int d = t >> 2;                  // 0..63
    int si = (t & 3) * 4;            // 0..12
    int b = (int)(rowbase >> 12);
    int sbase = (int)(rowbase & 4095);
    half4 v;
    for (int j = 0; j < 4; ++j) v[j] = (_Float16)Xs[si + j][d];
    *(half4*)(Vt + ((long)(b * 64 + d)) * SS + sbase + si) = v;
}

#define L2E 1.44269504088896340736f
#define PD 72   // LDS row pad: 144B stride -> 2-way (free) instead of 16-way on b128 frag reads

// Kernel B: flash attention partial over 1/NSPLIT of the keys.
// Computes S^T (A=K, B=Q) so each lane owns ONE query column: softmax reductions
// are in-lane + 2 shuffles each for max and sum; P-writes are key-contiguous b64.
__global__ __launch_bounds__(256, 4) void attn_partial(
    const _Float16* __restrict__ Qhi, const _Float16* __restrict__ Qlo,
    const _Float16* __restrict__ Khi, const _Float16* __restrict__ Klo,
    const _Float16* __restrict__ Vt,
    float* __restrict__ Op, float* __restrict__ Mp, float* __restrict__ Lp)
{
    __shared__ _Float16 Ksh[64][PD];
    __shared__ _Float16 Ksl[64][PD];
    __shared__ _Float16 Vs[64][PD];
    __shared__ _Float16 Ps[4][16][PD];   // [wave][query][key]

    int t = threadIdx.x;
    int wave = t >> 6;
    int lane = t & 63;
    int l15 = lane & 15;
    int quad = lane >> 4;
    int split = blockIdx.y;
    int b = blockIdx.z;
    int q0 = blockIdx.x * 64 + wave * 16;

    // Q fragments (B-operand for S^T): lane l15 = query col, k = quad*8+j
    long qrow = ((long)b * SS + q0 + l15) * DD;
    half8 qa0h = *(const half8*)(Qhi + qrow + quad * 8);
    half8 qa1h = *(const half8*)(Qhi + qrow + 32 + quad * 8);
    half8 qa0l = *(const half8*)(Qlo + qrow + quad * 8);
    half8 qa1l = *(const half8*)(Qlo + qrow + 32 + quad * 8);

    floatx4 o[4];
    for (int i = 0; i < 4; ++i) o[i] = (floatx4){0.f, 0.f, 0.f, 0.f};
    float m_q = -1e30f;   // running max for THIS lane's query (scaled/exp2 domain)
    float l_q = 0.f;

    const float scale = 0.125f * L2E;

    // staging addressing: each thread stages 2x16B per array
    int rr = t >> 2;
    int cc = (t & 3) * 16;
    long kbase = ((long)b * SS + rr) * DD + cc;
    long vbase = ((long)b * 64 + rr) * SS + cc;

    // prefetch tile 0 into registers
    int kt = split * KT_PER;
    uint4 rh0, rh1, rl0, rl1, rv0, rv1;
    {
        const uint4* khsrc = (const uint4*)(Khi + kbase + (long)kt * 64 * DD);
        rh0 = khsrc[0]; rh1 = khsrc[1];
        const uint4* klsrc = (const uint4*)(Klo + kbase + (long)kt * 64 * DD);
        rl0 = klsrc[0]; rl1 = klsrc[1];
        const uint4* vsrc = (const uint4*)(Vt + vbase + kt * 64);
        rv0 = vsrc[0]; rv1 = vsrc[1];
    }

    for (int i = 0; i < KT_PER; ++i) {
        if (i > 0) __syncthreads();          // previous tile's compute done
        {
            uint4* khdst = (uint4*)&Ksh[rr][cc];
            khdst[0] = rh0; khdst[1] = rh1;
            uint4* kldst = (uint4*)&Ksl[rr][cc];
            kldst[0] = rl0; kldst[1] = rl1;
            uint4* vdst = (uint4*)&Vs[rr][cc];
            vdst[0] = rv0; vdst[1] = rv1;
        }
        __syncthreads();                     // LDS tile ready

        // issue next tile's global loads (overlap with compute below)
        int ktn = (i + 1 < KT_PER) ? (kt + 1) : kt;   // clamp: harmless reload on last iter
        {
            const uint4* khsrc = (const uint4*)(Khi + kbase + (long)ktn * 64 * DD);
            rh0 = khsrc[0]; rh1 = khsrc[1];
            const uint4* klsrc = (const uint4*)(Klo + kbase + (long)ktn * 64 * DD);
            rl0 = klsrc[0]; rl1 = klsrc[1];
            const uint4* vsrc = (const uint4*)(Vt + vbase + ktn * 64);
            rv0 = vsrc[0]; rv1 = vsrc[1];
        }
        kt = ktn;

        // S^T = K Q^T (fp32-accurate via hi/lo): C[key=quad*4+r][query=l15]
        floatx4 s[4];
        for (int ct = 0; ct < 4; ++ct) {
            floatx4 acc = {0.f, 0.f, 0.f, 0.f};
            half8 ka0h = *(const half8*)&Ksh[ct * 16 + l15][quad * 8];
            half8 ka1h = *(const half8*)&Ksh[ct * 16 + l15][32 + quad * 8];
            half8 ka0l = *(const half8*)&Ksl[ct * 16 + l15][quad * 8];
            half8 ka1l = *(const half8*)&Ksl[ct * 16 + l15][32 + quad * 8];
            acc = __builtin_amdgcn_mfma_f32_16x16x32_f16(ka0h, qa0h, acc, 0, 0, 0);
            acc = __builtin_amdgcn_mfma_f32_16x16x32_f16(ka1h, qa1h, acc, 0, 0, 0);
            acc = __builtin_amdgcn_mfma_f32_16x16x32_f16(ka0h, qa0l, acc, 0, 0, 0);
            acc = __builtin_amdgcn_mfma_f32_16x16x32_f16(ka1h, qa1l, acc, 0, 0, 0);
            acc = __builtin_amdgcn_mfma_f32_16x16x32_f16(ka0l, qa0h, acc, 0, 0, 0);
            acc = __builtin_amdgcn_mfma_f32_16x16x32_f16(ka1l, qa1h, acc, 0, 0, 0);
            s[ct] = acc;
        }

        // per-lane query softmax: in-lane max over this lane's 16 keys,
        // then cross-quad reduction (lanes l15, l15+16, +32, +48 share a query)
        float mt = s[0][0];
        for (int ct = 0; ct < 4; ++ct)
            for (int r = 0; r < 4; ++r)
                mt = fmaxf(mt, s[ct][r]);
        mt = fmaxf(mt, __shfl_xor(mt, 16));
        mt = fmaxf(mt, __shfl_xor(mt, 32));
        mt *= scale;
        float mn = fmaxf(m_q, mt);
        float alpha = exp2f(m_q - mn);       // 0 on first tile
        m_q = mn;

        float rs = 0.f;
        for (int ct = 0; ct < 4; ++ct) {
            float p0 = exp2f(s[ct][0] * scale - mn);
            float p1 = exp2f(s[ct][1] * scale - mn);
            float p2 = exp2f(s[ct][2] * scale - mn);
            float p3 = exp2f(s[ct][3] * scale - mn);
            rs += (p0 + p1) + (p2 + p3);
            union { fp16x2 h2[2]; half4 h4; } u;
            u.h2[0] = __builtin_amdgcn_cvt_pkrtz(p0, p1);
            u.h2[1] = __builtin_amdgcn_cvt_pkrtz(p2, p3);
            // key-contiguous: Ps[query=l15][ct*16 + quad*4 .. +3], one b64 write
            *(half4*)&Ps[wave][l15][ct * 16 + quad * 4] = u.h4;
        }
        // cross-quad SUM: rs currently covers only this lane's 16 keys (the R5 bug)
        rs += __shfl_xor(rs, 16);
        rs += __shfl_xor(rs, 32);
        l_q = l_q * alpha + rs;

        // rescale O (C-layout rows = query quad*4+r): gather that query's alpha
        for (int r = 0; r < 4; ++r) {
            float a = __shfl(alpha, quad * 4 + r);
            o[0][r] *= a; o[1][r] *= a; o[2][r] *= a; o[3][r] *= a;
        }

        // O += P V : A = Ps (m=query, k=key), B = Vs rows (n=d, k=key)
        for (int h = 0; h < 2; ++h) {
            half8 pa = *(const half8*)&Ps[wave][l15][h * 32 + quad * 8];
            for (int dt = 0; dt < 4; ++dt) {
                half8 vb = *(const half8*)&Vs[dt * 16 + l15][h * 32 + quad * 8];
                o[dt] = __builtin_amdgcn_mfma_f32_16x16x32_f16(pa, vb, o[dt], 0, 0, 0);
            }
        }
    }

    // store unnormalized partial O (rows = query quad*4+r) and per-query (m, l)
    long pbase = ((long)b * NSPLIT + split) * SS;
    for (int r = 0; r < 4; ++r) {
        int q = q0 + quad * 4 + r;
        long orow = (pbase + q) * DD;
        for (int dt = 0; dt < 4; ++dt)
            Op[orow + dt * 16 + l15] = o[dt][r];
    }
    if (quad == 0) {
        Mp[pbase + q0 + l15] = m_q;
        Lp[pbase + q0 + l15] = l_q;
    }
}

// Kernel C: merge NSPLIT partials per query row. 16 queries/block.
__global__ __launch_bounds__(256) void combine_kernel(
    const float* __restrict__ Op, const float* __restrict__ Mp,
    const float* __restrict__ Lp, float* __restrict__ Out)
{
    int t = threadIdx.x;
    int qi = t >> 4;
    int d4 = (t & 15) * 4;
    long gq = (long)blockIdx.x * 16 + qi;    // global row in [0, BB*SS)
    int b = (int)(gq >> 12);
    int s = (int)(gq & 4095);

    float m = -1e30f;
    for (int i = 0; i < NSPLIT; ++i)
        m = fmaxf(m, Mp[((long)b * NSPLIT + i) * SS + s]);
    float l = 0.f;
    float4 o = {0.f, 0.f, 0.f, 0.f};
    for (int i = 0; i < NSPLIT; ++i) {
        long pb = ((long)b * NSPLIT + i) * SS + s;
        float a = exp2f(Mp[pb] - m);
        l = fmaf(Lp[pb], a, l);
        float4 oi = *(const float4*)(Op + pb * DD + d4);
        o.x = fmaf(oi.x, a, o.x); o.y = fmaf(oi.y, a, o.y);
        o.z = fmaf(oi.z, a, o.z); o.w = fmaf(oi.w, a, o.w);
    }
    float inv = 1.f / l;
    float4 r = {o.x * inv, o.y * inv, o.z * inv, o.w * inv};
    *(float4*)(Out + gq * DD + d4) = r;
}

extern "C" void kernel_launch(void* const* d_in, const int* in_sizes, int n_in,
                              void* d_out, int out_size, void* d_ws, size_t ws_size,
                              hipStream_t stream) {
    const float* X = (const float*)d_in[0];
    const float* R = (const float*)d_in[1];
    const float* E = (const float*)d_in[2];
    float* Out = (float*)d_out;

    const size_t N = (size_t)BB * SS * DD;
    _Float16* Qhi = (_Float16*)d_ws;
    _Float16* Qlo = Qhi + N;
    _Float16* Khi = Qlo + N;
    _Float16* Klo = Khi + N;
    _Float16* Vt  = Klo + N;                      // 10 MB fp16
    float* Op = (float*)(Vt + N);                 // BB*NSPLIT*SS*DD fp32 = 16.8 MB
    float* Mp = Op + (size_t)BB * NSPLIT * SS * DD;
    float* Lp = Mp + (size_t)BB * NSPLIT * SS;    // total ~27.3 MB

    proj_kernel<<<dim3(BB * SS / 16), 256, 0, stream>>>(X, R, E, Qhi, Qlo, Khi, Klo, Vt);
    attn_partial<<<dim3(SS / 64, NSPLIT, BB), 256, 0, stream>>>(Qhi, Qlo, Khi, Klo, Vt, Op, Mp, Lp);
    combine_kernel<<<dim3(BB * SS / 16), 256, 0, stream>>>(Op, Mp, Lp, Out);
}